// Round 1
// baseline (174.769 us; speedup 1.0000x reference)
//
#include <hip/hip_runtime.h>
#include <math.h>

#define CH 8
#define NH 4
#define HID 4
#define SPATIAL 65536   // 256*256
#define NSLICE 1024     // 32*4*8
#define EPS 1e-5f

// ---------------- Kernel 1: spatial mean pool ----------------
// one block per (b,h,c) slice of 65536 contiguous floats
__global__ void pool_kernel(const float* __restrict__ x, float* __restrict__ pooled) {
    const int slice = blockIdx.x;
    const float4* xs = (const float4*)(x + (size_t)slice * SPATIAL);
    float sum = 0.f;
    for (int k = threadIdx.x; k < SPATIAL / 4; k += blockDim.x) {
        float4 v = xs[k];
        sum += (v.x + v.y) + (v.z + v.w);
    }
    // wave (64-lane) reduce
    for (int off = 32; off; off >>= 1) sum += __shfl_down(sum, off, 64);
    __shared__ float part[4];
    const int lane = threadIdx.x & 63, wv = threadIdx.x >> 6;
    if (lane == 0) part[wv] = sum;
    __syncthreads();
    if (threadIdx.x == 0) {
        float s = (part[0] + part[1]) + (part[2] + part[3]);
        pooled[slice] = s * (1.0f / SPATIAL);
    }
}

// ---------------- Kernel 2: tiny attention + FFN on pooled ----------------
// 1 block, 128 threads; thread = b*NH + h owns one CH=8 row
__global__ void tiny_attn(const float* __restrict__ pooled,
                          const float* __restrict__ Wq, const float* __restrict__ Wk,
                          const float* __restrict__ Wv, const float* __restrict__ Wo,
                          const float* __restrict__ bo,
                          const float* __restrict__ W1, const float* __restrict__ b1,
                          const float* __restrict__ W2, const float* __restrict__ b2,
                          const float* __restrict__ g1, const float* __restrict__ beta1,
                          const float* __restrict__ g2, const float* __restrict__ beta2,
                          const float* __restrict__ gate,
                          float* __restrict__ factor) {
    const int tid = threadIdx.x;            // 0..127 = b*NH + h
    __shared__ float Kl[128][CH];
    __shared__ float Vl[128][CH];

    float xp[CH], xn[CH];
#pragma unroll
    for (int c = 0; c < CH; ++c) xp[c] = pooled[tid * CH + c];

    // LayerNorm 1
    float mu = 0.f;
#pragma unroll
    for (int c = 0; c < CH; ++c) mu += xp[c];
    mu *= (1.0f / CH);
    float var = 0.f;
#pragma unroll
    for (int c = 0; c < CH; ++c) { float d = xp[c] - mu; var += d * d; }
    var *= (1.0f / CH);
    float rs = rsqrtf(var + EPS);
#pragma unroll
    for (int c = 0; c < CH; ++c) xn[c] = (xp[c] - mu) * rs * g1[c] + beta1[c];

    // Q,K,V  (row @ W.T  ->  out[c] = sum_j xn[j]*W[c*CH+j])
    float Q[CH];
#pragma unroll
    for (int c = 0; c < CH; ++c) {
        float q = 0.f, k = 0.f, v = 0.f;
#pragma unroll
        for (int j = 0; j < CH; ++j) {
            q += xn[j] * Wq[c * CH + j];
            k += xn[j] * Wk[c * CH + j];
            v += xn[j] * Wv[c * CH + j];
        }
        Q[c] = q; Kl[tid][c] = k; Vl[tid][c] = v;
    }
    __syncthreads();

    // scores across heads within batch
    const int b4 = (tid >> 2) << 2;         // first row of this batch
    const float scale = 0.35355339059327373f;  // CH^-0.5
    float sc[NH], mx = -1e30f;
#pragma unroll
    for (int g = 0; g < NH; ++g) {
        float s = 0.f;
#pragma unroll
        for (int c = 0; c < CH; ++c) s += Q[c] * Kl[b4 + g][c];
        s *= scale;
        sc[g] = s;
        mx = fmaxf(mx, s);
    }
    float den = 0.f;
#pragma unroll
    for (int g = 0; g < NH; ++g) { sc[g] = __expf(sc[g] - mx); den += sc[g]; }
    const float inv = 1.0f / den;

    float ao[CH];
#pragma unroll
    for (int c = 0; c < CH; ++c) {
        float a = 0.f;
#pragma unroll
        for (int g = 0; g < NH; ++g) a += sc[g] * Vl[b4 + g][c];
        ao[c] = a * inv;
    }

    // out proj + residual
    float xa[CH];
#pragma unroll
    for (int c = 0; c < CH; ++c) {
        float o = bo[c];
#pragma unroll
        for (int j = 0; j < CH; ++j) o += ao[j] * Wo[c * CH + j];
        xa[c] = xp[c] + o;
    }

    // LayerNorm 2
    mu = 0.f;
#pragma unroll
    for (int c = 0; c < CH; ++c) mu += xa[c];
    mu *= (1.0f / CH);
    var = 0.f;
#pragma unroll
    for (int c = 0; c < CH; ++c) { float d = xa[c] - mu; var += d * d; }
    var *= (1.0f / CH);
    rs = rsqrtf(var + EPS);
    float xn2[CH];
#pragma unroll
    for (int c = 0; c < CH; ++c) xn2[c] = (xa[c] - mu) * rs * g2[c] + beta2[c];

    // FFN: gelu(xn2 @ W1.T + b1) @ W2.T + b2   (exact gelu)
    float h1[HID];
#pragma unroll
    for (int i = 0; i < HID; ++i) {
        float t = b1[i];
#pragma unroll
        for (int c = 0; c < CH; ++c) t += xn2[c] * W1[i * CH + c];
        h1[i] = 0.5f * t * (1.0f + erff(t * 0.70710678118654752f));
    }

    const float gs = 1.0f / (1.0f + __expf(-gate[0]));
#pragma unroll
    for (int c = 0; c < CH; ++c) {
        float f = b2[c];
#pragma unroll
        for (int i = 0; i < HID; ++i) f += h1[i] * W2[c * HID + i];
        float xo = xa[c] + f;
        float aw = gs * (xo - xp[c]) + xp[c];
        factor[tid * CH + c] = 1.0f + aw;
    }
}

// ---------------- Kernel 3: broadcast scale ----------------
__global__ void scale_kernel(const float* __restrict__ x,
                             const float* __restrict__ factor,
                             float* __restrict__ out, long n4) {
    long i = (long)blockIdx.x * blockDim.x + threadIdx.x;
    const long stride = (long)gridDim.x * blockDim.x;
    const float4* x4 = (const float4*)x;
    float4* o4 = (float4*)out;
    for (; i < n4; i += stride) {
        const float f = factor[i >> 14];   // 16384 float4 per slice
        float4 v = x4[i];
        v.x *= f; v.y *= f; v.z *= f; v.w *= f;
        o4[i] = v;
    }
}

extern "C" void kernel_launch(void* const* d_in, const int* in_sizes, int n_in,
                              void* d_out, int out_size, void* d_ws, size_t ws_size,
                              hipStream_t stream) {
    const float* x     = (const float*)d_in[0];
    const float* Wq    = (const float*)d_in[1];
    const float* Wk    = (const float*)d_in[2];
    const float* Wv    = (const float*)d_in[3];
    const float* Wo    = (const float*)d_in[4];
    const float* bo    = (const float*)d_in[5];
    const float* W1    = (const float*)d_in[6];
    const float* b1    = (const float*)d_in[7];
    const float* W2    = (const float*)d_in[8];
    const float* b2    = (const float*)d_in[9];
    const float* g1    = (const float*)d_in[10];
    const float* beta1 = (const float*)d_in[11];
    const float* g2    = (const float*)d_in[12];
    const float* beta2 = (const float*)d_in[13];
    const float* gate  = (const float*)d_in[14];
    float* out = (float*)d_out;

    float* pooled = (float*)d_ws;            // NSLICE floats
    float* factor = pooled + NSLICE;         // NSLICE floats

    pool_kernel<<<NSLICE, 256, 0, stream>>>(x, pooled);
    tiny_attn<<<1, 128, 0, stream>>>(pooled, Wq, Wk, Wv, Wo, bo,
                                     W1, b1, W2, b2, g1, beta1, g2, beta2,
                                     gate, factor);
    const long n4 = (long)NSLICE * (SPATIAL / 4);
    scale_kernel<<<2048, 256, 0, stream>>>(x, factor, out, n4);
}

// Round 2
// 130.150 us; speedup vs baseline: 1.3428x; 1.3428x over previous
//
#include <hip/hip_runtime.h>
#include <math.h>

#define CH 8
#define NH 4
#define HID 4
#define SPATIAL 65536   // 256*256
#define NSLICE 1024     // 32*4*8
#define EPS 1e-5f

typedef float nf4 __attribute__((ext_vector_type(4)));

// ---------------- Kernel 1: spatial mean pool ----------------
// one block per (b,h,c) slice of 65536 contiguous floats
__global__ void pool_kernel(const float* __restrict__ x, float* __restrict__ pooled) {
    const int slice = blockIdx.x;
    const nf4* xs = (const nf4*)(x + (size_t)slice * SPATIAL);
    float sum = 0.f;
    for (int k = threadIdx.x; k < SPATIAL / 4; k += blockDim.x) {
        nf4 v = xs[k];
        sum += (v.x + v.y) + (v.z + v.w);
    }
    // wave (64-lane) reduce
    for (int off = 32; off; off >>= 1) sum += __shfl_down(sum, off, 64);
    __shared__ float part[4];
    const int lane = threadIdx.x & 63, wv = threadIdx.x >> 6;
    if (lane == 0) part[wv] = sum;
    __syncthreads();
    if (threadIdx.x == 0) {
        float s = (part[0] + part[1]) + (part[2] + part[3]);
        pooled[slice] = s * (1.0f / SPATIAL);
    }
}

// ---------------- Kernel 2: fused factor-compute + broadcast scale ----------------
// grid = NSLICE*2 blocks of 256 threads; block (slice, half) covers 8192 float4.
// Lanes 0..3 redundantly compute the tiny cross-head attention for this block's
// batch (4 rows of CH=8 from `pooled`), producing the per-(h,c) scale factor.
// Output is written with NON-TEMPORAL stores so x stays resident in the 256 MB
// Infinity Cache after the pool pass -> this kernel's x reads are L3 hits.
__global__ __launch_bounds__(256, 4)
void scale_fused(const float* __restrict__ x,
                 const float* __restrict__ pooled,
                 const float* __restrict__ Wq, const float* __restrict__ Wk,
                 const float* __restrict__ Wv, const float* __restrict__ Wo,
                 const float* __restrict__ bo,
                 const float* __restrict__ W1, const float* __restrict__ b1,
                 const float* __restrict__ W2, const float* __restrict__ b2,
                 const float* __restrict__ g1, const float* __restrict__ beta1,
                 const float* __restrict__ g2, const float* __restrict__ beta2,
                 const float* __restrict__ gate,
                 float* __restrict__ out) {
    const int blk   = blockIdx.x;
    const int slice = blk >> 1;          // (b*4 + h)*8 + c
    const int half  = blk & 1;
    const int b     = slice >> 5;
    const int hh    = (slice >> 3) & 3;
    const int cc    = slice & 7;
    const int tid   = threadIdx.x;

    __shared__ float Kl[NH][CH], Vl[NH][CH], fac[NH][CH];

    float xp[CH], Q[CH];
    if (tid < NH) {
        // row h = tid of batch b
        const float* pr = pooled + b * (NH * CH) + tid * CH;
#pragma unroll
        for (int c = 0; c < CH; ++c) xp[c] = pr[c];
        // LayerNorm 1
        float mu = 0.f;
#pragma unroll
        for (int c = 0; c < CH; ++c) mu += xp[c];
        mu *= 0.125f;
        float var = 0.f;
#pragma unroll
        for (int c = 0; c < CH; ++c) { float d = xp[c] - mu; var += d * d; }
        var *= 0.125f;
        float rs = rsqrtf(var + EPS);
        float xn[CH];
#pragma unroll
        for (int c = 0; c < CH; ++c) xn[c] = (xp[c] - mu) * rs * g1[c] + beta1[c];
        // Q,K,V
#pragma unroll
        for (int c = 0; c < CH; ++c) {
            float q = 0.f, k = 0.f, v = 0.f;
#pragma unroll
            for (int j = 0; j < CH; ++j) {
                q += xn[j] * Wq[c * CH + j];
                k += xn[j] * Wk[c * CH + j];
                v += xn[j] * Wv[c * CH + j];
            }
            Q[c] = q; Kl[tid][c] = k; Vl[tid][c] = v;
        }
    }
    __syncthreads();
    if (tid < NH) {
        // scores across the 4 heads of this batch
        float sc[NH], mx = -1e30f;
#pragma unroll
        for (int g = 0; g < NH; ++g) {
            float s = 0.f;
#pragma unroll
            for (int c = 0; c < CH; ++c) s += Q[c] * Kl[g][c];
            s *= 0.35355339059327373f;   // CH^-0.5
            sc[g] = s; mx = fmaxf(mx, s);
        }
        float den = 0.f;
#pragma unroll
        for (int g = 0; g < NH; ++g) { sc[g] = __expf(sc[g] - mx); den += sc[g]; }
        const float inv = 1.0f / den;
        float ao[CH];
#pragma unroll
        for (int c = 0; c < CH; ++c) {
            float a = 0.f;
#pragma unroll
            for (int g = 0; g < NH; ++g) a += sc[g] * Vl[g][c];
            ao[c] = a * inv;
        }
        // out proj + residual
        float xa[CH];
#pragma unroll
        for (int c = 0; c < CH; ++c) {
            float o = bo[c];
#pragma unroll
            for (int j = 0; j < CH; ++j) o += ao[j] * Wo[c * CH + j];
            xa[c] = xp[c] + o;
        }
        // LayerNorm 2
        float mu = 0.f;
#pragma unroll
        for (int c = 0; c < CH; ++c) mu += xa[c];
        mu *= 0.125f;
        float var = 0.f;
#pragma unroll
        for (int c = 0; c < CH; ++c) { float d = xa[c] - mu; var += d * d; }
        var *= 0.125f;
        float rs = rsqrtf(var + EPS);
        float xn2[CH];
#pragma unroll
        for (int c = 0; c < CH; ++c) xn2[c] = (xa[c] - mu) * rs * g2[c] + beta2[c];
        // FFN (exact gelu)
        float h1[HID];
#pragma unroll
        for (int i = 0; i < HID; ++i) {
            float t = b1[i];
#pragma unroll
            for (int c = 0; c < CH; ++c) t += xn2[c] * W1[i * CH + c];
            h1[i] = 0.5f * t * (1.0f + erff(t * 0.70710678118654752f));
        }
        const float gs = 1.0f / (1.0f + __expf(-gate[0]));
#pragma unroll
        for (int c = 0; c < CH; ++c) {
            float f = b2[c];
#pragma unroll
            for (int i = 0; i < HID; ++i) f += h1[i] * W2[c * HID + i];
            float xo = xa[c] + f;
            fac[tid][c] = 1.0f + gs * (xo - xp[c]) + xp[c];
        }
    }
    __syncthreads();
    const float f = fac[hh][cc];

    const nf4* xs = (const nf4*)x   + (size_t)slice * (SPATIAL / 4) + (size_t)half * 8192;
    nf4*       os = (nf4*)out       + (size_t)slice * (SPATIAL / 4) + (size_t)half * 8192;
    for (int k = tid; k < 8192; k += 256) {
        nf4 v = xs[k];
        v *= f;
        __builtin_nontemporal_store(v, &os[k]);   // don't evict x from L3
    }
}

extern "C" void kernel_launch(void* const* d_in, const int* in_sizes, int n_in,
                              void* d_out, int out_size, void* d_ws, size_t ws_size,
                              hipStream_t stream) {
    const float* x     = (const float*)d_in[0];
    const float* Wq    = (const float*)d_in[1];
    const float* Wk    = (const float*)d_in[2];
    const float* Wv    = (const float*)d_in[3];
    const float* Wo    = (const float*)d_in[4];
    const float* bo    = (const float*)d_in[5];
    const float* W1    = (const float*)d_in[6];
    const float* b1    = (const float*)d_in[7];
    const float* W2    = (const float*)d_in[8];
    const float* b2    = (const float*)d_in[9];
    const float* g1    = (const float*)d_in[10];
    const float* beta1 = (const float*)d_in[11];
    const float* g2    = (const float*)d_in[12];
    const float* beta2 = (const float*)d_in[13];
    const float* gate  = (const float*)d_in[14];
    float* out = (float*)d_out;

    float* pooled = (float*)d_ws;            // NSLICE floats

    pool_kernel<<<NSLICE, 256, 0, stream>>>(x, pooled);
    scale_fused<<<NSLICE * 2, 256, 0, stream>>>(x, pooled,
                                                Wq, Wk, Wv, Wo, bo,
                                                W1, b1, W2, b2,
                                                g1, beta1, g2, beta2,
                                                gate, out);
}